// Round 4
// baseline (257.098 us; speedup 1.0000x reference)
//
#include <hip/hip_runtime.h>
#include <hip/hip_bf16.h>
#include <stdint.h>
#include <stddef.h>

typedef __bf16 bf16_t;
typedef __bf16 bf16x8 __attribute__((ext_vector_type(8)));
typedef float  f32x4  __attribute__((ext_vector_type(4)));

#define NN 1024
#define H  128
#define GRID 8192   // 1-wave blocks; each handles 8 tiles of 16 rows

// ---------------- We fp32 -> bf16 ----------------
__global__ void k_cvt_we(const float* __restrict__ src, bf16_t* __restrict__ dst) {
    int i = blockIdx.x * 256 + threadIdx.x;
    if (i < H * H) dst[i] = (bf16_t)src[i];
}

// ---------------- f_i = node @ Wi^T, f_j = node @ Wj^T ----------------
__global__ void k_proj(const float* __restrict__ node,
                       const float* __restrict__ Wi,
                       const float* __restrict__ Wj,
                       bf16_t* __restrict__ fi,
                       bf16_t* __restrict__ fj) {
    __shared__ float nrow[H];
    const int row = blockIdx.x;
    const int t   = threadIdx.x;
    const int h   = t & (H - 1);
    const int sel = t >> 7;
    if (t < H) nrow[t] = node[(size_t)row * H + t];
    __syncthreads();
    const float* w = (sel ? Wj : Wi) + (size_t)h * H;
    float acc = 0.f;
    #pragma unroll
    for (int k4 = 0; k4 < H / 4; ++k4) {
        f32x4 wv = *(const f32x4*)(w + k4 * 4);
        f32x4 nv = *(const f32x4*)(&nrow[k4 * 4]);
        acc += nv[0] * wv[0] + nv[1] * wv[1] + nv[2] * wv[2] + nv[3] * wv[3];
    }
    bf16_t* dst = sel ? fj : fi;
    dst[(size_t)row * H + h] = (bf16_t)acc;
}

// ---------------- dots[i][j] = f_i[i] . f_j[j] ----------------
__global__ __launch_bounds__(256, 4)
void k_dots(const bf16_t* __restrict__ fi,
            const bf16_t* __restrict__ fj,
            float* __restrict__ dots) {
    const int t    = threadIdx.x;
    const int wave = t >> 6;
    const int lane = t & 63;
    const int l15  = lane & 15;
    const int g    = lane >> 4;

    const int bm    = blockIdx.x >> 3;
    const int bn    = blockIdx.x & 7;
    const int ibase = bm * 128 + wave * 32;
    const int jbase = bn * 128;

    f32x4 acc[2][8];
    #pragma unroll
    for (int mf = 0; mf < 2; ++mf)
        #pragma unroll
        for (int nt = 0; nt < 8; ++nt)
            acc[mf][nt] = (f32x4){0.f, 0.f, 0.f, 0.f};

    const bf16_t* a0 = fi + (size_t)(ibase +  0 + l15) * H + g * 8;
    const bf16_t* a1 = fi + (size_t)(ibase + 16 + l15) * H + g * 8;

    #pragma unroll
    for (int kst = 0; kst < 4; ++kst) {
        bf16x8 af0 = *(const bf16x8*)(a0 + kst * 32);
        bf16x8 af1 = *(const bf16x8*)(a1 + kst * 32);
        #pragma unroll
        for (int nt = 0; nt < 8; ++nt) {
            bf16x8 bf = *(const bf16x8*)(fj + (size_t)(jbase + nt * 16 + l15) * H + kst * 32 + g * 8);
            acc[0][nt] = __builtin_amdgcn_mfma_f32_16x16x32_bf16(af0, bf, acc[0][nt], 0, 0, 0);
            acc[1][nt] = __builtin_amdgcn_mfma_f32_16x16x32_bf16(af1, bf, acc[1][nt], 0, 0, 0);
        }
    }

    #pragma unroll
    for (int mf = 0; mf < 2; ++mf) {
        const int rbase = ibase + mf * 16 + g * 4;
        #pragma unroll
        for (int r = 0; r < 4; ++r) {
            #pragma unroll
            for (int nt = 0; nt < 8; ++nt)
                dots[(size_t)(rbase + r) * NN + jbase + nt * 16 + l15] = acc[mf][nt][r];
        }
    }
}

// ---------------- async global -> LDS (16B/lane, dest = uniform base + lane*16) ----------------
__device__ __forceinline__ void gl_lds16(const float* g, float* l) {
    __builtin_amdgcn_global_load_lds(
        (const __attribute__((address_space(1))) unsigned int*)g,
        (__attribute__((address_space(3))) unsigned int*)l,
        16, 0, 0);
}

// ---------------- main: out = relu(edge @ We^T + be + dots[row]) ----------------
// 1-wave blocks. Wave owns 16 rows/tile, 8 tiles (strided by GRID). Depth-2
// prefetch through 3 LDS buffers via global_load_lds (in-loop VMEM = exactly
// 8 staging loads + 8 stores -> counted vmcnt works). We/bias/dots pinned in
// VGPRs with identity-asm so the compiler cannot rematerialize loads in-loop.
// LDS XOR-swizzle (rule #21): linear dest, inverse-swizzled global source,
// swizzled ds_read -> 2-way conflicts only.
__global__ __launch_bounds__(64, 2)
void k_main(const float* __restrict__ edge,   // [1M][128] fp32
            const bf16_t* __restrict__ web,   // [128][128] bf16
            const float* __restrict__ be,     // [128]
            const float* __restrict__ dots,   // [1M]
            float* __restrict__ out) {        // [1M][128] fp32
    __shared__ __align__(16) float buf[3][16][H];   // 24 KB

    const int lane  = threadIdx.x;      // 0..63
    const int l15   = lane & 15;
    const int g     = lane >> 4;
    const int lhalf = lane >> 5;            // staging: which row of the pair
    const int b16   = (lane & 31) * 16;     // staging: byte within 512B row

    // ---- prologue loads, all pinned in registers ----
    bf16x8 wfr[8][4];
    {
        const bf16_t* wp = web + (size_t)l15 * H + g * 8;
        #pragma unroll
        for (int nt = 0; nt < 8; ++nt)
            #pragma unroll
            for (int kk = 0; kk < 4; ++kk)
                wfr[nt][kk] = *(const bf16x8*)(wp + (size_t)(nt * 16) * H + kk * 32);
    }
    f32x4 bvv[8];
    #pragma unroll
    for (int nt = 0; nt < 8; ++nt)
        bvv[nt] = *(const f32x4*)(be + nt * 16 + g * 4);

    float dvv[8];
    #pragma unroll
    for (int k = 0; k < 8; ++k)
        dvv[k] = dots[(size_t)(blockIdx.x + k * GRID) * 16 + l15];

    #pragma unroll
    for (int nt = 0; nt < 8; ++nt) {
        #pragma unroll
        for (int kk = 0; kk < 4; ++kk)
            asm volatile("" : "+v"(wfr[nt][kk]));
        asm volatile("" : "+v"(bvv[nt]));
        asm volatile("" : "+v"(dvv[nt]));
    }

    // ---- staging: LDS linear, global source pre-swizzled (involution) ----
    #define STAGE(K, BI)                                                         \
        {                                                                        \
            const char* tb = (const char*)(edge + (size_t)(blockIdx.x + (K) * GRID) * 16 * H); \
            _Pragma("unroll")                                                    \
            for (int i = 0; i < 8; ++i) {                                        \
                const int r = 2 * i + lhalf;                                     \
                const int srcoff = r * 512 + (b16 ^ ((r & 7) << 4));             \
                gl_lds16((const float*)(tb + srcoff), &buf[BI][2 * i][0]);       \
            }                                                                    \
        }

    STAGE(0, 0)
    STAGE(1, 1)

    const int sw = (l15 & 7) << 4;   // read-side swizzle (same involution)

    #pragma unroll
    for (int k = 0; k < 8; ++k) {
        // wait for tile k's staging loads (in-order retirement: the N newest
        // outstanding ops are younger stores/loads; everything older retires)
        if (k == 0)                 asm volatile("s_waitcnt vmcnt(8)"  ::: "memory");
        else if (k == 1 || k == 7)  asm volatile("s_waitcnt vmcnt(16)" ::: "memory");
        else                        asm volatile("s_waitcnt vmcnt(24)" ::: "memory");
        __builtin_amdgcn_sched_barrier(0);

        if (k < 6) STAGE(k + 2, (k + 2) % 3)

        const float dv = dvv[k];
        f32x4 acc[8];
        #pragma unroll
        for (int nt = 0; nt < 8; ++nt) {
            #pragma unroll
            for (int r = 0; r < 4; ++r) acc[nt][r] = bvv[nt][r] + dv;
        }

        const char* lrow = (const char*)&buf[k % 3][0][0] + l15 * 512;
        #pragma unroll
        for (int kk = 0; kk < 4; ++kk) {
            f32x4 u0 = *(const f32x4*)(lrow + kk * 128 + ((g * 32 +  0) ^ sw));
            f32x4 u1 = *(const f32x4*)(lrow + kk * 128 + ((g * 32 + 16) ^ sw));
            bf16x8 bfrag;
            #pragma unroll
            for (int i2 = 0; i2 < 4; ++i2) {
                bfrag[i2]     = (bf16_t)u0[i2];
                bfrag[i2 + 4] = (bf16_t)u1[i2];
            }
            #pragma unroll
            for (int nt = 0; nt < 8; ++nt)
                acc[nt] = __builtin_amdgcn_mfma_f32_16x16x32_bf16(wfr[nt][kk], bfrag, acc[nt], 0, 0, 0);
        }

        float* op = out + ((size_t)(blockIdx.x + k * GRID) * 16 + l15) * H + g * 4;
        #pragma unroll
        for (int nt = 0; nt < 8; ++nt) {
            f32x4 v;
            #pragma unroll
            for (int r = 0; r < 4; ++r) v[r] = fmaxf(acc[nt][r], 0.f);
            *(f32x4*)(op + nt * 16) = v;
        }
    }
    #undef STAGE
}

extern "C" void kernel_launch(void* const* d_in, const int* in_sizes, int n_in,
                              void* d_out, int out_size, void* d_ws, size_t ws_size,
                              hipStream_t stream) {
    const float* node = (const float*)d_in[0];
    const float* edge = (const float*)d_in[1];
    const float* We   = (const float*)d_in[2];
    const float* be   = (const float*)d_in[3];
    const float* Wi   = (const float*)d_in[4];
    const float* Wj   = (const float*)d_in[5];
    float* out = (float*)d_out;

    char* w = (char*)d_ws;
    bf16_t* fi_bf = (bf16_t*)w;                              // 256 KB
    bf16_t* fj_bf = (bf16_t*)(w + (256 << 10));              // 256 KB
    float*  dots  = (float*)(w + (512 << 10));               // 4 MB
    bf16_t* web   = (bf16_t*)(w + (512 << 10) + (4 << 20));  // 32 KB

    k_cvt_we<<<(H * H + 255) / 256, 256, 0, stream>>>(We, web);
    k_proj<<<NN, 256, 0, stream>>>(node, Wi, Wj, fi_bf, fj_bf);
    k_dots<<<64, 256, 0, stream>>>(fi_bf, fj_bf, dots);
    k_main<<<GRID, 64, 0, stream>>>(edge, web, be, dots, out);
}

// Round 5
// 244.939 us; speedup vs baseline: 1.0496x; 1.0496x over previous
//
#include <hip/hip_runtime.h>
#include <hip/hip_bf16.h>
#include <stdint.h>
#include <stddef.h>

typedef __bf16 bf16_t;
typedef __bf16 bf16x8 __attribute__((ext_vector_type(8)));
typedef float  f32x4  __attribute__((ext_vector_type(4)));

#define NN 1024
#define H  128
#define GRID 2048   // 256-thr blocks; each block: 8 tiles of 64 rows (16 rows/wave)

// ---------------- We fp32 -> bf16 ----------------
__global__ void k_cvt_we(const float* __restrict__ src, bf16_t* __restrict__ dst) {
    int i = blockIdx.x * 256 + threadIdx.x;
    if (i < H * H) dst[i] = (bf16_t)src[i];
}

// ---------------- f_i = node @ Wi^T, f_j = node @ Wj^T ----------------
__global__ void k_proj(const float* __restrict__ node,
                       const float* __restrict__ Wi,
                       const float* __restrict__ Wj,
                       bf16_t* __restrict__ fi,
                       bf16_t* __restrict__ fj) {
    __shared__ float nrow[H];
    const int row = blockIdx.x;
    const int t   = threadIdx.x;
    const int h   = t & (H - 1);
    const int sel = t >> 7;
    if (t < H) nrow[t] = node[(size_t)row * H + t];
    __syncthreads();
    const float* w = (sel ? Wj : Wi) + (size_t)h * H;
    float acc = 0.f;
    #pragma unroll
    for (int k4 = 0; k4 < H / 4; ++k4) {
        f32x4 wv = *(const f32x4*)(w + k4 * 4);
        f32x4 nv = *(const f32x4*)(&nrow[k4 * 4]);
        acc += nv[0] * wv[0] + nv[1] * wv[1] + nv[2] * wv[2] + nv[3] * wv[3];
    }
    bf16_t* dst = sel ? fj : fi;
    dst[(size_t)row * H + h] = (bf16_t)acc;
}

// ---------------- dots[i][j] = f_i[i] . f_j[j]  (grid 128: 16x8 tiles of 64x128) ----------------
__global__ __launch_bounds__(256, 4)
void k_dots(const bf16_t* __restrict__ fi,
            const bf16_t* __restrict__ fj,
            float* __restrict__ dots) {
    const int t    = threadIdx.x;
    const int wave = t >> 6;
    const int lane = t & 63;
    const int l15  = lane & 15;
    const int g    = lane >> 4;

    const int bm    = blockIdx.x >> 3;    // 0..15
    const int bn    = blockIdx.x & 7;     // 0..7
    const int ibase = bm * 64 + wave * 16;
    const int jbase = bn * 128;

    f32x4 acc[8];
    #pragma unroll
    for (int nt = 0; nt < 8; ++nt) acc[nt] = (f32x4){0.f, 0.f, 0.f, 0.f};

    const bf16_t* a = fi + (size_t)(ibase + l15) * H + g * 8;

    #pragma unroll
    for (int kst = 0; kst < 4; ++kst) {
        bf16x8 af = *(const bf16x8*)(a + kst * 32);
        #pragma unroll
        for (int nt = 0; nt < 8; ++nt) {
            bf16x8 bf = *(const bf16x8*)(fj + (size_t)(jbase + nt * 16 + l15) * H + kst * 32 + g * 8);
            acc[nt] = __builtin_amdgcn_mfma_f32_16x16x32_bf16(af, bf, acc[nt], 0, 0, 0);
        }
    }

    const int rbase = ibase + g * 4;
    #pragma unroll
    for (int r = 0; r < 4; ++r)
        #pragma unroll
        for (int nt = 0; nt < 8; ++nt)
            dots[(size_t)(rbase + r) * NN + jbase + nt * 16 + l15] = acc[nt][r];
}

// ---------------- async global -> LDS (16B/lane, dest = uniform base + lane*16) ----------------
__device__ __forceinline__ void gl_lds16(const float* g, float* l) {
    __builtin_amdgcn_global_load_lds(
        (const __attribute__((address_space(1))) unsigned int*)g,
        (__attribute__((address_space(3))) unsigned int*)l,
        16, 0, 0);
}

// ---------------- main: out = relu(edge @ We^T + be + dots[row]) ----------------
// 4-wave blocks, wave-private 16-row slices, depth-1 prefetch through TWO
// SEPARATE __shared__ objects (bufA/bufB: distinct base objects -> alias
// analysis proves ds_read/gl_lds disjoint -> no hidden vmcnt(0) before the
// fragment reads). Per iteration: wait -> ds_read tile k to regs -> stage
// tile k+1 -> MFMA -> stores. In-loop VMEM = exactly 8 gl_lds + 8 stores,
// so counted vmcnt(8) is exact. We-fragments + dots pinned in VGPRs.
__global__ __launch_bounds__(256, 2)
void k_main(const float* __restrict__ edge,   // [1M][128] fp32
            const bf16_t* __restrict__ web,   // [128][128] bf16
            const float* __restrict__ be,     // [128]
            const float* __restrict__ dots,   // [1M]
            float* __restrict__ out) {        // [1M][128] fp32
    __shared__ __align__(16) float bufA[64][H];   // 32 KB
    __shared__ __align__(16) float bufB[64][H];   // 32 KB
    __shared__ float lbias[H];

    const int t     = threadIdx.x;
    const int wave  = t >> 6;
    const int lane  = t & 63;
    const int l15   = lane & 15;
    const int g     = lane >> 4;
    const int lhalf = lane >> 5;            // staging: which row of the pair
    const int b16   = (lane & 31) * 16;     // staging: byte within 512B row

    if (t < H) lbias[t] = be[t];
    __syncthreads();

    // ---- prologue: pinned register state (web fragments + dots) ----
    bf16x8 wfr[8][4];
    {
        const bf16_t* wp = web + (size_t)l15 * H + g * 8;
        #pragma unroll
        for (int nt = 0; nt < 8; ++nt)
            #pragma unroll
            for (int kk = 0; kk < 4; ++kk)
                wfr[nt][kk] = *(const bf16x8*)(wp + (size_t)(nt * 16) * H + kk * 32);
    }
    float dvv[8];
    #pragma unroll
    for (int k = 0; k < 8; ++k)
        dvv[k] = dots[(size_t)(blockIdx.x + k * GRID) * 64 + wave * 16 + l15];

    #pragma unroll
    for (int nt = 0; nt < 8; ++nt) {
        #pragma unroll
        for (int kk = 0; kk < 4; ++kk)
            asm volatile("" : "+v"(wfr[nt][kk]));
        asm volatile("" : "+v"(dvv[nt]));
    }
    // Pins force the compiler to drain the prologue loads HERE, so the loop's
    // vmem queue holds only staging loads + stores.

    // ---- staging: LDS linear dest, global source pre-swizzled (involution) ----
    #define STAGE(K, BUFP)                                                       \
        {                                                                        \
            const char* tb = (const char*)(edge + ((size_t)(blockIdx.x + (K) * GRID) * 64 + wave * 16) * H); \
            _Pragma("unroll")                                                    \
            for (int i = 0; i < 8; ++i) {                                        \
                const int r = 2 * i + lhalf;                                     \
                const int srcoff = r * 512 + (b16 ^ ((r & 7) << 4));             \
                gl_lds16((const float*)(tb + srcoff), &BUFP[wave * 16 + 2 * i][0]); \
            }                                                                    \
        }

    STAGE(0, bufA)

    const int sw = (l15 & 7) << 4;   // read-side swizzle (same involution)

    #pragma unroll
    for (int k = 0; k < 8; ++k) {
        // tile k staged? in-loop vmem/iter = 8 gl_lds + 8 stores ->
        // younger-than-stage(k) at this point = stores(k-1) = 8 (0 at k=0).
        if (k == 0) asm volatile("s_waitcnt vmcnt(0)" ::: "memory");
        else        asm volatile("s_waitcnt vmcnt(8)" ::: "memory");
        __builtin_amdgcn_sched_barrier(0);

        // 1) fragment reads FIRST (before any new gl_lds in program order)
        const char* lrow = (const char*)((k & 1) ? &bufB[0][0] : &bufA[0][0])
                         + (wave * 16 + l15) * 512;
        f32x4 u[8];
        #pragma unroll
        for (int kk = 0; kk < 4; ++kk) {
            u[2 * kk]     = *(const f32x4*)(lrow + kk * 128 + ((g * 32 +  0) ^ sw));
            u[2 * kk + 1] = *(const f32x4*)(lrow + kk * 128 + ((g * 32 + 16) ^ sw));
        }

        // 2) stage tile k+1 into the OTHER buffer (stays in flight across MFMA)
        if (k < 7) {
            if (k & 1) { STAGE(k + 1, bufA) }
            else       { STAGE(k + 1, bufB) }
        }

        // 3) acc init = bias (LDS broadcast) + dot, then MFMA from regs
        const float dv = dvv[k];
        f32x4 acc[8];
        #pragma unroll
        for (int nt = 0; nt < 8; ++nt) {
            f32x4 bv = *(const f32x4*)(&lbias[nt * 16 + g * 4]);
            #pragma unroll
            for (int r = 0; r < 4; ++r) acc[nt][r] = bv[r] + dv;
        }

        #pragma unroll
        for (int kk = 0; kk < 4; ++kk) {
            bf16x8 bfrag;
            #pragma unroll
            for (int i2 = 0; i2 < 4; ++i2) {
                bfrag[i2]     = (bf16_t)u[2 * kk][i2];
                bfrag[i2 + 4] = (bf16_t)u[2 * kk + 1][i2];
            }
            #pragma unroll
            for (int nt = 0; nt < 8; ++nt)
                acc[nt] = __builtin_amdgcn_mfma_f32_16x16x32_bf16(wfr[nt][kk], bfrag, acc[nt], 0, 0, 0);
        }

        // 4) stores (16 rows x 64B per instruction)
        float* op = out + ((size_t)(blockIdx.x + k * GRID) * 64 + wave * 16 + l15) * H + g * 4;
        #pragma unroll
        for (int nt = 0; nt < 8; ++nt) {
            f32x4 v;
            #pragma unroll
            for (int r = 0; r < 4; ++r) v[r] = fmaxf(acc[nt][r], 0.f);
            *(f32x4*)(op + nt * 16) = v;
        }
    }
    #undef STAGE
}

extern "C" void kernel_launch(void* const* d_in, const int* in_sizes, int n_in,
                              void* d_out, int out_size, void* d_ws, size_t ws_size,
                              hipStream_t stream) {
    const float* node = (const float*)d_in[0];
    const float* edge = (const float*)d_in[1];
    const float* We   = (const float*)d_in[2];
    const float* be   = (const float*)d_in[3];
    const float* Wi   = (const float*)d_in[4];
    const float* Wj   = (const float*)d_in[5];
    float* out = (float*)d_out;

    char* w = (char*)d_ws;
    bf16_t* fi_bf = (bf16_t*)w;                              // 256 KB
    bf16_t* fj_bf = (bf16_t*)(w + (256 << 10));              // 256 KB
    float*  dots  = (float*)(w + (512 << 10));               // 4 MB
    bf16_t* web   = (bf16_t*)(w + (512 << 10) + (4 << 20));  // 32 KB

    k_cvt_we<<<(H * H + 255) / 256, 256, 0, stream>>>(We, web);
    k_proj<<<NN, 256, 0, stream>>>(node, Wi, Wj, fi_bf, fj_bf);
    k_dots<<<128, 256, 0, stream>>>(fi_bf, fj_bf, dots);
    k_main<<<GRID, 256, 0, stream>>>(edge, web, be, dots, out);
}